// Round 9
// baseline (61.524 us; speedup 1.0000x reference)
//
#include <hip/hip_runtime.h>
#include <math.h>

#define T     600
#define C     14
#define NOUT  500
#define W     128        // steps per window
#define NWIN  5
#define DSTR  132        // D-buffer row stride (floats) — bank spread
#define CAP   64         // max (t,mask) events per row
#define XSW   1792       // floats per xs buffer (448 granules * 4)

typedef float f32x2 __attribute__((ext_vector_type(2)));

__device__ __forceinline__ void stage16(const float* gp, float* lp) {
    __builtin_amdgcn_global_load_lds(
        (const __attribute__((address_space(1))) void*)(gp),
        (__attribute__((address_space(3))) void*)(lp), 16, 0, 0);
}

__global__ __launch_bounds__(64)
void snn_v9(const float* __restrict__ x, const float* __restrict__ W1,
            const float* __restrict__ W2, float* __restrict__ out) {
    __shared__ float    xs[2 * XSW];     // 14336 B: double-buffered x windows
    __shared__ float    db[C * DSTR];    // 7392 B: D window (padded rows)
    __shared__ unsigned evs[CAP];        // (t<<14) | 14-bit channel mask

    const int  lane = threadIdx.x;
    const long row  = blockIdx.x;
    const float* xr = &x[row * (long)(C * T)];
    const int  ce   = (lane < C) ? lane : (C - 1);   // chain source channel

    // ---- staging: slot s=64k+lane; j=s>>5; g=(s-j)&31 (swizzled source) ----
    const float* gsrc[7];
    int gk[7];
    #pragma unroll
    for (int k = 0; k < 7; ++k) {
        const int s = 64 * k + lane;
        const int j = s >> 5;
        gk[k] = (s - j) & 31;                        // granule index (swizzle)
        gsrc[k] = xr + j * T + 4 * gk[k];
    }
    // ---- GEMM LDS read byte-offsets (per channel, within a buffer) ----
    int xadr[C];
    #pragma unroll
    for (int j = 0; j < C; ++j)
        xadr[j] = 16 * (32 * j + (((lane >> 1) + j) & 31)) + 8 * (lane & 1);

    // ---- prologue: issue windows 0 and 1 (14 loads in flight) ----
    #pragma unroll
    for (int k = 0; k < 7; ++k) stage16(gsrc[k],     &xs[k * 256]);
    #pragma unroll
    for (int k = 0; k < 7; ++k) stage16(gsrc[k] + W, &xs[XSW + k * 256]);

    float v1 = 0.f;
    int   ecnt = 0;                      // wave-uniform event count

    for (int w = 0; w < NWIN; ++w) {
        const int t0 = w * W;
        // older window landed; newer 7 loads may stay in flight
        if (w == NWIN - 1) asm volatile("s_waitcnt vmcnt(0)" ::: "memory");
        else               asm volatile("s_waitcnt vmcnt(7)" ::: "memory");
        __builtin_amdgcn_sched_barrier(0);

        // ===== GEMM: D[c][t-pair] = sum_j W1[c][j] * (0.5*x[j]) =====
        const char* xb = (const char*)&xs[(w & 1) * XSW];
        f32x2 xv[C];
        #pragma unroll
        for (int j = 0; j < C; ++j)
            xv[j] = *(const f32x2*)(xb + xadr[j]);
        // tail window: steps >= 88 get D=0 (stale LDS masked out, exact)
        const float msk = (w == NWIN - 1 && 2 * lane >= T - 512) ? 0.f : 0.5f;
        #pragma unroll
        for (int j = 0; j < C; ++j) { xv[j].x *= msk; xv[j].y *= msk; }
        #pragma unroll
        for (int c = 0; c < C; ++c) {
            f32x2 a = {0.f, 0.f};
            #pragma unroll
            for (int j = 0; j < C; ++j) {
                const float wv = W1[c * C + j];
                a.x = fmaf(xv[j].x, wv, a.x);
                a.y = fmaf(xv[j].y, wv, a.y);
            }
            *(f32x2*)&db[c * DSTR + 2 * lane] = a;
        }
        asm volatile("s_waitcnt lgkmcnt(0)" ::: "memory");  // xs reads done
        __builtin_amdgcn_sched_barrier(0);

        // ===== issue window w+2 into the buffer just read =====
        if (w + 2 < NWIN) {
            float* lb = &xs[(w & 1) * XSW];
            if (w + 2 < NWIN - 1) {
                #pragma unroll
                for (int k = 0; k < 7; ++k) {
                    gsrc[k] += W;
                    stage16(gsrc[k] + W, lb + k * 256);
                }
            } else {                       // tail: only granules with t < T
                #pragma unroll
                for (int k = 0; k < 7; ++k) {
                    gsrc[k] += W;
                    if (4 * gk[k] < T - 512)            // 88 valid steps
                        stage16(gsrc[k] + W, lb + k * 256);
                }
            }
        }

        // ===== LIF-1 chain: spec-16 batches, LDS prefetch 1 batch ahead =====
        const float* dp = &db[ce * DSTR];
        const int nb = (w < NWIN - 1) ? 8 : 6;   // 128 or 96 (88 + zero pad)
        float4 c0 = *(const float4*)&dp[0];
        float4 c1 = *(const float4*)&dp[4];
        float4 c2 = *(const float4*)&dp[8];
        float4 c3 = *(const float4*)&dp[12];
        for (int b = 0; b < nb; ++b) {
            float4 n0, n1, n2, n3;
            const bool more = (b + 1 < nb);
            if (more) {
                const float* np_ = dp + 16 * (b + 1);
                n0 = *(const float4*)&np_[0];
                n1 = *(const float4*)&np_[4];
                n2 = *(const float4*)&np_[8];
                n3 = *(const float4*)&np_[12];
            }
            float h[16];
            h[0]=c0.x; h[1]=c0.y; h[2]=c0.z; h[3]=c0.w;
            h[4]=c1.x; h[5]=c1.y; h[6]=c1.z; h[7]=c1.w;
            h[8]=c2.x; h[9]=c2.y; h[10]=c2.z; h[11]=c2.w;
            h[12]=c3.x; h[13]=c3.y; h[14]=c3.z; h[15]=c3.w;

            float vv = v1;
            float m0 = -1e30f, m1 = -1e30f, m2 = -1e30f, m3 = -1e30f;
            #pragma unroll
            for (int u = 0; u < 16; u += 4) {    // 4 parallel max chains
                vv = fmaf(vv, 0.5f, h[u]);     m0 = fmaxf(m0, vv);
                vv = fmaf(vv, 0.5f, h[u + 1]); m1 = fmaxf(m1, vv);
                vv = fmaf(vv, 0.5f, h[u + 2]); m2 = fmaxf(m2, vv);
                vv = fmaf(vv, 0.5f, h[u + 3]); m3 = fmaxf(m3, vv);
            }
            const float mx = fmaxf(fmaxf(m0, m1), fmaxf(m2, m3));

            if (__builtin_expect(__ballot(mx >= 7.0f) != 0ull, 0)) {
                float vp = v1;                   // exact replay with resets
                #pragma unroll
                for (int u = 0; u < 16; ++u) {
                    vp = fmaf(vp, 0.5f, h[u]);
                    const unsigned long long bal = __ballot(vp >= 7.0f);
                    if (bal) {
                        if (vp >= 7.0f) vp = 0.5f;   // reset + exact cache fold
                        if (lane == 0 && ecnt < CAP)
                            evs[ecnt] = ((unsigned)(t0 + 16 * b + u) << 14)
                                      | ((unsigned)bal & 0x3FFFu);
                        ++ecnt;                      // wave-uniform
                    }
                }
                v1 = vp;
            } else {
                v1 = vv;                             // no spike: bitwise exact
            }
            if (more) { c0 = n0; c1 = n1; c2 = n2; c3 = n3; }
        }
    }

    asm volatile("s_waitcnt lgkmcnt(0)" ::: "memory");
    __builtin_amdgcn_sched_barrier(0);

    // ===== event-driven LIF-2 + exp: 64 lanes x 8 outputs =====
    const int n = (ecnt < CAP) ? ecnt : CAP;
    float v2[8];
    #pragma unroll
    for (int k = 0; k < 8; ++k) v2[k] = 0.f;
    int tprev = -1;

    for (int e = 0; e < n; ++e) {
        const unsigned ev = evs[e];
        const int t = (int)(ev >> 14);
        unsigned mm = ev & 0x3FFFu;
        float i2[8];
        #pragma unroll
        for (int k = 0; k < 8; ++k) i2[k] = 0.f;
        while (mm) {                         // ascending channels = ref dot order
            const int c = (int)__builtin_ctz(mm);
            mm &= mm - 1;
            #pragma unroll
            for (int k = 0; k < 8; ++k) {
                const int o = lane + (k << 6);
                if (o < NOUT) i2[k] += W2[o * C + c];
            }
        }
        const int gap = t - tprev - 1;
        if (gap > 0) {                       // exact pure-decay run
            #pragma unroll
            for (int k = 0; k < 8; ++k) v2[k] = ldexpf(v2[k], -gap);
        }
        #pragma unroll
        for (int k = 0; k < 8; ++k) {
            const float v = v2[k] + (i2[k] - v2[k]) * 0.5f;   // ref-order charge
            v2[k] = (v >= 7.0f) ? 0.f : v;                    // hard reset
        }
        tprev = t;
    }
    {
        const int gap = (T - 1) - tprev;
        if (gap > 0) {
            #pragma unroll
            for (int k = 0; k < 8; ++k) v2[k] = ldexpf(v2[k], -gap);
        }
    }
    #pragma unroll
    for (int k = 0; k < 8; ++k) {
        const int o = lane + (k << 6);
        if (o < NOUT) out[row * NOUT + o] = expf(v2[k]);
    }
}

extern "C" void kernel_launch(void* const* d_in, const int* in_sizes, int n_in,
                              void* d_out, int out_size, void* d_ws, size_t ws_size,
                              hipStream_t stream) {
    const float* x  = (const float*)d_in[0];
    const float* W1 = (const float*)d_in[1];
    const float* W2 = (const float*)d_in[2];
    float* o = (float*)d_out;
    const int B = in_sizes[0] / (C * T);     // 4096
    snn_v9<<<B, 64, 0, stream>>>(x, W1, W2, o);
}

// Round 10
// 54.717 us; speedup vs baseline: 1.1244x; 1.1244x over previous
//
#include <hip/hip_runtime.h>
#include <math.h>

#define T     600
#define C     14
#define NOUT  500
#define W     128        // steps per window (64 lanes x 2)
#define NWIN  5
#define DSTR  132        // D row stride (floats): 2-way-free bank spread
#define CAP   64         // max (t,mask) events per row

typedef float f32x2 __attribute__((ext_vector_type(2)));

__device__ __forceinline__ f32x2 fma2(f32x2 a, f32x2 b, f32x2 c) {
#if __has_builtin(__builtin_elementwise_fma)
    return __builtin_elementwise_fma(a, b, c);    // v_pk_fma_f32
#else
    f32x2 r; r.x = fmaf(a.x, b.x, c.x); r.y = fmaf(a.y, b.y, c.y); return r;
#endif
}

__global__ __launch_bounds__(64)
void snn_v10(const float* __restrict__ x, const float* __restrict__ W1,
             const float* __restrict__ W2, float* __restrict__ out) {
    __shared__ float    db[C * DSTR];    // 7392 B: D window
    __shared__ unsigned evs[CAP];        // (t<<14) | 14-bit channel mask

    const int  lane = threadIdx.x;
    const long row  = blockIdx.x;
    const float* xr = &x[row * (long)(C * T)];
    const int  ce   = (lane < C) ? lane : (C - 1);   // chain source channel

    // ---- prefetch window 0 into registers (compiler schedules waits) ----
    f32x2 xv[C];
    #pragma unroll
    for (int j = 0; j < C; ++j)
        xv[j] = *(const f32x2*)&xr[j * T + 2 * lane];

    float v1 = 0.f;
    int   ecnt = 0;                      // wave-uniform event count

    for (int w = 0; w < NWIN; ++w) {
        const int t0 = w * W;

        // ---- fold 0.5*x (exact), mask tail steps >= 88 to zero D ----
        const float mk = (w == NWIN - 1 && 2 * lane >= T - 512) ? 0.f : 0.5f;
        f32x2 xh[C];
        #pragma unroll
        for (int j = 0; j < C; ++j) { xh[j].x = xv[j].x * mk; xh[j].y = xv[j].y * mk; }

        // ---- issue next-window loads (free to float across the window) ----
        if (w + 1 < NWIN) {
            int tn = t0 + W + 2 * lane;
            if (tn + 1 >= T) tn = 0;                 // clamp; masked at next fold
            #pragma unroll
            for (int j = 0; j < C; ++j)
                xv[j] = *(const f32x2*)&xr[j * T + tn];
        }

        // ---- GEMM: D[c][t-pair] = sum_j W1[c][j] * (0.5 x[j])  (pk_fma) ----
        #pragma unroll
        for (int c = 0; c < C; ++c) {
            f32x2 a = {0.f, 0.f};
            #pragma unroll
            for (int j = 0; j < C; ++j) {
                const float wvv = W1[c * C + j];
                const f32x2 wb = {wvv, wvv};
                a = fma2(xh[j], wb, a);
            }
            *(f32x2*)&db[c * DSTR + 2 * lane] = a;
        }

        // ---- LIF-1 chain: spec-16 batches, LDS prefetch 1 batch ahead ----
        // (same-wave LDS ordering: compiler inserts precise lgkmcnt waits)
        const float* dp = &db[ce * DSTR];
        const int nb = (w < NWIN - 1) ? 8 : 6;   // 128 or 96 (88 + zero pad)
        float4 c0 = *(const float4*)&dp[0];
        float4 c1 = *(const float4*)&dp[4];
        float4 c2 = *(const float4*)&dp[8];
        float4 c3 = *(const float4*)&dp[12];
        for (int b = 0; b < nb; ++b) {
            float4 n0, n1, n2, n3;
            const bool more = (b + 1 < nb);
            if (more) {
                const float* np_ = dp + 16 * (b + 1);
                n0 = *(const float4*)&np_[0];
                n1 = *(const float4*)&np_[4];
                n2 = *(const float4*)&np_[8];
                n3 = *(const float4*)&np_[12];
            }
            float h[16];
            h[0]=c0.x; h[1]=c0.y; h[2]=c0.z; h[3]=c0.w;
            h[4]=c1.x; h[5]=c1.y; h[6]=c1.z; h[7]=c1.w;
            h[8]=c2.x; h[9]=c2.y; h[10]=c2.z; h[11]=c2.w;
            h[12]=c3.x; h[13]=c3.y; h[14]=c3.z; h[15]=c3.w;

            float vv = v1;
            float m0 = -1e30f, m1 = -1e30f, m2 = -1e30f, m3 = -1e30f;
            #pragma unroll
            for (int u = 0; u < 16; u += 4) {    // 4 parallel max chains
                vv = fmaf(vv, 0.5f, h[u]);     m0 = fmaxf(m0, vv);
                vv = fmaf(vv, 0.5f, h[u + 1]); m1 = fmaxf(m1, vv);
                vv = fmaf(vv, 0.5f, h[u + 2]); m2 = fmaxf(m2, vv);
                vv = fmaf(vv, 0.5f, h[u + 3]); m3 = fmaxf(m3, vv);
            }
            const float mx = fmaxf(fmaxf(m0, m1), fmaxf(m2, m3));

            if (__builtin_expect(__ballot(mx >= 7.0f) != 0ull, 0)) {
                float vp = v1;                   // exact replay with resets
                #pragma unroll
                for (int u = 0; u < 16; ++u) {
                    vp = fmaf(vp, 0.5f, h[u]);
                    const unsigned long long bal = __ballot(vp >= 7.0f);
                    if (bal) {
                        if (vp >= 7.0f) vp = 0.5f;   // reset + exact cache fold
                        if (lane == 0 && ecnt < CAP)
                            evs[ecnt] = ((unsigned)(t0 + 16 * b + u) << 14)
                                      | ((unsigned)bal & 0x3FFFu);
                        ++ecnt;                      // wave-uniform
                    }
                }
                v1 = vp;
            } else {
                v1 = vv;                             // no spike: bitwise exact
            }
            if (more) { c0 = n0; c1 = n1; c2 = n2; c3 = n3; }
        }
    }

    // ===== event-driven LIF-2 + exp: 64 lanes x 8 outputs =====
    // (evs written by this wave; in-order LDS, no fence needed)
    const int n = (ecnt < CAP) ? ecnt : CAP;
    float v2[8];
    #pragma unroll
    for (int k = 0; k < 8; ++k) v2[k] = 0.f;
    int tprev = -1;

    for (int e = 0; e < n; ++e) {
        const unsigned ev = evs[e];
        const int t = (int)(ev >> 14);
        unsigned mm = ev & 0x3FFFu;
        float i2[8];
        #pragma unroll
        for (int k = 0; k < 8; ++k) i2[k] = 0.f;
        while (mm) {                         // ascending channels = ref dot order
            const int c = (int)__builtin_ctz(mm);
            mm &= mm - 1;
            #pragma unroll
            for (int k = 0; k < 8; ++k) {
                const int o = lane + (k << 6);
                if (o < NOUT) i2[k] += W2[o * C + c];
            }
        }
        const int gap = t - tprev - 1;
        if (gap > 0) {                       // exact pure-decay run
            #pragma unroll
            for (int k = 0; k < 8; ++k) v2[k] = ldexpf(v2[k], -gap);
        }
        #pragma unroll
        for (int k = 0; k < 8; ++k) {
            const float v = v2[k] + (i2[k] - v2[k]) * 0.5f;   // ref-order charge
            v2[k] = (v >= 7.0f) ? 0.f : v;                    // hard reset
        }
        tprev = t;
    }
    {
        const int gap = (T - 1) - tprev;
        if (gap > 0) {
            #pragma unroll
            for (int k = 0; k < 8; ++k) v2[k] = ldexpf(v2[k], -gap);
        }
    }
    #pragma unroll
    for (int k = 0; k < 8; ++k) {
        const int o = lane + (k << 6);
        if (o < NOUT) out[row * NOUT + o] = expf(v2[k]);
    }
}

extern "C" void kernel_launch(void* const* d_in, const int* in_sizes, int n_in,
                              void* d_out, int out_size, void* d_ws, size_t ws_size,
                              hipStream_t stream) {
    const float* x  = (const float*)d_in[0];
    const float* W1 = (const float*)d_in[1];
    const float* W2 = (const float*)d_in[2];
    float* o = (float*)d_out;
    const int B = in_sizes[0] / (C * T);     // 4096
    snn_v10<<<B, 64, 0, stream>>>(x, W1, W2, o);
}